// Round 6
// baseline (6982.557 us; speedup 1.0000x reference)
//
#include <hip/hip_runtime.h>

// Problem constants
#define Tt    1024
#define INF   256
#define Hh    768
#define OUTF  128

// Grid: 48 L0 + 48 L1 + 2 LIN compute WGs + 1 coordinator WG. 1024 thr each.
#define NWG_L0  48
#define NWG_L1  48
#define NWG_LIN 2
#define NWGC    (NWG_L0 + NWG_L1 + NWG_LIN)   // 98 compute WGs
#define NWG     (NWGC + 1)                     // +1 coordinator
#define NTHR    1024

typedef unsigned int       u32;
typedef unsigned long long u64;
typedef unsigned short     u16;
typedef __attribute__((ext_vector_type(8))) short bf16x8;   // 8 bf16 = 4 VGPRs
typedef __attribute__((ext_vector_type(4))) float f32x4;    // MFMA C/D

// ws layout (bytes). Every flag on a PRIVATE 128-B line (1 writer, 1 reader).
#define PROG_OFF 0         // prog[wg] = ws + wg*128       (writer: WG leader; reader: coordinator lane wg)
#define GO_OFF   16384     // go[wg]   = ws + GO_OFF+wg*128(writer: coordinator lane wg; reader: WG leader)
#define HA_OFF   32768     // hA ring: [2 parity][32 b][768 j] bf16 (2*48 KB)
#define HB_OFF   131072    // hB ring: same
#define WS_BYTES 229376
#define HPS 24576          // ring parity stride in u16 (32*768)

#define ASTR_B 1552        // act LDS row stride bytes (776 bf16; 388 dw % 32 == 4)
// red: [32 slabs][16 n][16 m] f32, padded: slab stride 272 dw, n-row stride 17 dw
#define RSLAB 272
#define RROW  17
#define HPACK_OFF 34816    // after red (32*272*4 = 34816 B); act dead by then

__device__ __forceinline__ float sigf(float v){ return 1.0f/(1.0f+__expf(-v)); }
__device__ __forceinline__ float tanhfast(float x){
    const float cx = fminf(fmaxf(x, -15.f), 15.f);
    const float e  = __expf(2.f * cx);
    return (e - 1.f) / (e + 1.f);
}
__device__ __forceinline__ u16 f2bf(float f){           // round-nearest-even
    u32 u = __float_as_uint(f);
    return (u16)((u + 0x7fffu + ((u>>16)&1u)) >> 16);
}
// LLC-coherent (cache-bypassing) accesses for cross-WG data (R3/R5-proven).
__device__ __forceinline__ u64 ld64ws(const u16* p){
    return __hip_atomic_load((const u64*)p, __ATOMIC_RELAXED, __HIP_MEMORY_SCOPE_AGENT);
}
__device__ __forceinline__ void st32ws(u16* p, u32 v){
    __hip_atomic_store((u32*)p, v, __ATOMIC_RELAXED, __HIP_MEMORY_SCOPE_AGENT);
}
__device__ __forceinline__ u32 ldu32(const u32* p){
    return __hip_atomic_load(p, __ATOMIC_RELAXED, __HIP_MEMORY_SCOPE_AGENT);
}
__device__ __forceinline__ void stu32(u32* p, u32 v){
    __hip_atomic_store(p, v, __ATOMIC_RELAXED, __HIP_MEMORY_SCOPE_AGENT);
}

__global__ void prologue(char* ws){
    int i = blockIdx.x * 256 + threadIdx.x;
    if (i < WS_BYTES / 4)   // uncached stores so LLC readers see zeros immediately
        __hip_atomic_store(((u32*)ws) + i, 0u, __ATOMIC_RELAXED, __HIP_MEMORY_SCOPE_AGENT);
}

__device__ __forceinline__ bf16x8 load8w(const float* p){
    float4 v0 = *(const float4*)(p);
    float4 v1 = *(const float4*)(p + 4);
    bf16x8 r;
    r[0]=(short)f2bf(v0.x); r[1]=(short)f2bf(v0.y); r[2]=(short)f2bf(v0.z); r[3]=(short)f2bf(v0.w);
    r[4]=(short)f2bf(v1.x); r[5]=(short)f2bf(v1.y); r[6]=(short)f2bf(v1.z); r[7]=(short)f2bf(v1.w);
    return r;
}

__global__ __launch_bounds__(NTHR) void lstm_persist(
    const float* __restrict__ x,
    const float* __restrict__ Wih0, const float* __restrict__ Whh0,
    const float* __restrict__ bih0, const float* __restrict__ bhh0,
    const float* __restrict__ Wih1, const float* __restrict__ Whh1,
    const float* __restrict__ bih1, const float* __restrict__ bhh1,
    const float* __restrict__ Wlin, const float* __restrict__ blin,
    float* __restrict__ out, char* ws)
{
    u32* prog = (u32*)(ws + PROG_OFF);
    u32* gol  = (u32*)(ws + GO_OFF);
    u16* hA   = (u16*)(ws + HA_OFF);
    u16* hB   = (u16*)(ws + HB_OFF);

    const int wg  = blockIdx.x;
    const int tid = threadIdx.x;

    __shared__ __align__(16) char smem[49664];

    // ============== coordinator WG: 2 waves, ballot-AND, private fanout ==============
    if (wg == NWGC) {
        u32* cflag = (u32*)smem;          // [2] cross-wave handshake
        if (tid < 2) cflag[tid] = 0;
        __syncthreads();                   // all 16 waves present here
        const int wv = tid >> 6;
        if (wv >= 2) return;               // idle waves exit; no further __syncthreads
        const int lane = tid & 63;
        const int line = wv * 64 + lane;
        const bool valid = (line < NWGC);
        for (int s = 0; s < Tt + 2; ++s) {
            const u32 tg = (u32)(s + 1);
            bool mine = !valid;
            int guard = 0;
            while (guard < (1 << 27)) {
                if (!mine) mine = (ldu32(prog + line * 32) >= tg);
                if (__ballot(mine) == ~0ull) break;
                ++guard;
            }
            __hip_atomic_store(&cflag[wv], tg, __ATOMIC_RELAXED, __HIP_MEMORY_SCOPE_WORKGROUP);
            guard = 0;
            while (__hip_atomic_load(&cflag[1 - wv], __ATOMIC_RELAXED, __HIP_MEMORY_SCOPE_WORKGROUP) < tg
                   && guard < (1 << 27)) ++guard;
            if (valid) stu32(gol + line * 32, tg);
        }
        return;
    }

    // ============== compute WGs ==============
    char*  actb  = smem;                       // [32 b][776 bf16] staging (per chunk)
    float* red   = (float*)smem;               // padded slabs; aliases act after MFMAs
    u16*   hpack = (u16*)(smem + HPACK_OFF);   // [16 j][32 b] bf16

    const int lane = tid & 63, w = tid >> 6;
    const int quad = lane >> 4, nl = lane & 15;
    const int nt = w >> 2, ks = w & 3;         // n-tile 0..3, K-slice 0..3
    const int b3 = tid >> 5, q = tid & 31;     // staging map: batch row, col-block

    const int role  = (wg < NWG_L0) ? 0 : ((wg < NWG_L0 + NWG_L1) ? 1 : 2);
    const int jbase = (role == 0) ? wg * 16 : ((role == 1) ? (wg - NWG_L0) * 16 : 0);
    const int obase = (role == 2) ? (wg - NWG_L0 - NWG_L1) * 64 : 0;

    // ---- register-resident bf16 weights (B-frags), loaded ONCE ----
    // B-frag layout (R4-verified): n = lane&15, k = quad*8 + j.
    bf16x8 bfr[12];
    if (role == 0) {
        const int grow = nt * Hh + jbase + nl;
        #pragma unroll
        for (int fi = 0; fi < 8; ++fi) {
            const int c = fi >> 2, fc = fi & 3;
            const int ka = c * 512 + ks * 128 + fc * 32 + quad * 8;   // K: [x(256); hA(768)]
            const float* p = (ka < 256) ? (Wih0 + (size_t)grow * 256 + ka)
                                        : (Whh0 + (size_t)grow * 768 + (ka - 256));
            bfr[fi] = load8w(p);
        }
    } else if (role == 1) {
        const int grow = nt * Hh + jbase + nl;
        #pragma unroll
        for (int fi = 0; fi < 12; ++fi) {
            const int c = fi / 6, fc = fi % 6;
            const int ka = c * 768 + ks * 192 + fc * 32 + quad * 8;   // K: [hA; hB]
            const float* p = (ka < 768) ? (Wih1 + (size_t)grow * 768 + ka)
                                        : (Whh1 + (size_t)grow * 768 + (ka - 768));
            bfr[fi] = load8w(p);
        }
    } else {
        const int row = obase + nt * 16 + nl;
        #pragma unroll
        for (int fi = 0; fi < 6; ++fi) {
            const int ka = ks * 192 + fi * 32 + quad * 8;
            bfr[fi] = load8w(Wlin + (size_t)row * 768 + ka);
        }
    }

    // gate-thread constants + c-state in registers (thread owns (jl,b) forever)
    float bs0 = 0.f, bs1 = 0.f, bs2 = 0.f, bs3 = 0.f, creg = 0.f, bl0 = 0.f, bl1 = 0.f;
    if (role < 2 && tid < 512) {
        const int jg = jbase + (tid >> 5);
        const float* bi = (role == 0) ? bih0 : bih1;
        const float* bh = (role == 0) ? bhh0 : bhh1;
        bs0 = bi[jg]        + bh[jg];
        bs1 = bi[768 + jg]  + bh[768 + jg];
        bs2 = bi[1536 + jg] + bh[1536 + jg];
        bs3 = bi[2304 + jg] + bh[2304 + jg];
    }
    if (role == 2) {
        bl0 = blin[obase + (tid >> 5)];
        bl1 = blin[obase + 32 + (tid >> 5)];
    }

    for (int s = 0; s < Tt + 2; ++s) {
        // ---- wait for release of step s (private go line) ----
        if (s > 0) {
            if (tid == 0) {
                int guard = 0;
                while (ldu32(gol + wg * 32) < (u32)s && guard < (1 << 27)) {
                    __builtin_amdgcn_s_sleep(1); ++guard;
                }
            }
            __syncthreads();
        }

        const bool active = (role == 0) ? (s < Tt)
                          : (role == 1) ? (s >= 1 && s <= Tt)
                          :               (s >= 2);

        if (active) {
            f32x4 acc0 = {0.f,0.f,0.f,0.f}, acc1 = {0.f,0.f,0.f,0.f};

            if (role == 0) {
                // ---- ALL global loads up front (single LLC latency exposure) ----
                const float* xs = x + ((size_t)b3 * Tt + s) * INF + q * 8;
                const float4 v0 = *(const float4*)xs;
                const float4 v1 = *(const float4*)(xs + 4);
                const u16* hp = hA + (size_t)((s + 1) & 1) * HPS + b3 * 768;
                const u64 c0a = ld64ws(hp + q * 8);
                const u64 c0b = ld64ws(hp + q * 8 + 4);
                u64 c1r[4];
                #pragma unroll
                for (int p = 0; p < 2; ++p) {
                    c1r[2*p]   = ld64ws(hp + 256 + q * 8 + 256 * p);
                    c1r[2*p+1] = ld64ws(hp + 256 + q * 8 + 256 * p + 4);
                }
                // chunk 0: cols [0,256)=x(t), [256,512)=hA[0,256)
                {
                    const u64 xlo = (u64)f2bf(v0.x) | ((u64)f2bf(v0.y)<<16) | ((u64)f2bf(v0.z)<<32) | ((u64)f2bf(v0.w)<<48);
                    const u64 xhi = (u64)f2bf(v1.x) | ((u64)f2bf(v1.y)<<16) | ((u64)f2bf(v1.z)<<32) | ((u64)f2bf(v1.w)<<48);
                    u64* dx = (u64*)(actb + b3 * ASTR_B + q * 16);
                    dx[0] = xlo; dx[1] = xhi;
                    u64* dh = (u64*)(actb + b3 * ASTR_B + (256 + q * 8) * 2);
                    dh[0] = c0a; dh[1] = c0b;
                }
                __syncthreads();
                #pragma unroll
                for (int fc = 0; fc < 4; ++fc) {
                    const int koff = ks * 128 + fc * 32 + quad * 8;
                    bf16x8 a0 = *(const bf16x8*)(actb + nl * ASTR_B + koff * 2);
                    bf16x8 a1 = *(const bf16x8*)(actb + (16 + nl) * ASTR_B + koff * 2);
                    acc0 = __builtin_amdgcn_mfma_f32_16x16x32_bf16(a0, bfr[fc], acc0, 0, 0, 0);
                    acc1 = __builtin_amdgcn_mfma_f32_16x16x32_bf16(a1, bfr[fc], acc1, 0, 0, 0);
                }
                __syncthreads();
                // chunk 1: cols [0,512) = hA[256,768) (from regs)
                #pragma unroll
                for (int p = 0; p < 2; ++p) {
                    u64* d = (u64*)(actb + b3 * ASTR_B + (q * 8 + 256 * p) * 2);
                    d[0] = c1r[2*p]; d[1] = c1r[2*p+1];
                }
                __syncthreads();
                #pragma unroll
                for (int fc = 0; fc < 4; ++fc) {
                    const int koff = ks * 128 + fc * 32 + quad * 8;
                    bf16x8 a0 = *(const bf16x8*)(actb + nl * ASTR_B + koff * 2);
                    bf16x8 a1 = *(const bf16x8*)(actb + (16 + nl) * ASTR_B + koff * 2);
                    acc0 = __builtin_amdgcn_mfma_f32_16x16x32_bf16(a0, bfr[4 + fc], acc0, 0, 0, 0);
                    acc1 = __builtin_amdgcn_mfma_f32_16x16x32_bf16(a1, bfr[4 + fc], acc1, 0, 0, 0);
                }
                __syncthreads();
            } else if (role == 1) {
                const int u = s - 1;
                const u16* bA = hA + (size_t)(u & 1) * HPS + b3 * 768;
                const u16* bB = hB + (size_t)((u + 1) & 1) * HPS + b3 * 768;
                u64 rA[6], rB[6];
                #pragma unroll
                for (int p = 0; p < 3; ++p) {
                    rA[2*p]   = ld64ws(bA + q * 8 + 256 * p);
                    rA[2*p+1] = ld64ws(bA + q * 8 + 256 * p + 4);
                    rB[2*p]   = ld64ws(bB + q * 8 + 256 * p);
                    rB[2*p+1] = ld64ws(bB + q * 8 + 256 * p + 4);
                }
                #pragma unroll
                for (int p = 0; p < 3; ++p) {
                    u64* d = (u64*)(actb + b3 * ASTR_B + (q * 8 + 256 * p) * 2);
                    d[0] = rA[2*p]; d[1] = rA[2*p+1];
                }
                __syncthreads();
                #pragma unroll
                for (int fc = 0; fc < 6; ++fc) {
                    const int koff = ks * 192 + fc * 32 + quad * 8;
                    bf16x8 a0 = *(const bf16x8*)(actb + nl * ASTR_B + koff * 2);
                    bf16x8 a1 = *(const bf16x8*)(actb + (16 + nl) * ASTR_B + koff * 2);
                    acc0 = __builtin_amdgcn_mfma_f32_16x16x32_bf16(a0, bfr[fc], acc0, 0, 0, 0);
                    acc1 = __builtin_amdgcn_mfma_f32_16x16x32_bf16(a1, bfr[fc], acc1, 0, 0, 0);
                }
                __syncthreads();
                #pragma unroll
                for (int p = 0; p < 3; ++p) {
                    u64* d = (u64*)(actb + b3 * ASTR_B + (q * 8 + 256 * p) * 2);
                    d[0] = rB[2*p]; d[1] = rB[2*p+1];
                }
                __syncthreads();
                #pragma unroll
                for (int fc = 0; fc < 6; ++fc) {
                    const int koff = ks * 192 + fc * 32 + quad * 8;
                    bf16x8 a0 = *(const bf16x8*)(actb + nl * ASTR_B + koff * 2);
                    bf16x8 a1 = *(const bf16x8*)(actb + (16 + nl) * ASTR_B + koff * 2);
                    acc0 = __builtin_amdgcn_mfma_f32_16x16x32_bf16(a0, bfr[6 + fc], acc0, 0, 0, 0);
                    acc1 = __builtin_amdgcn_mfma_f32_16x16x32_bf16(a1, bfr[6 + fc], acc1, 0, 0, 0);
                }
                __syncthreads();
            } else {
                const u16* base = hB + (size_t)((s - 2) & 1) * HPS + b3 * 768;
                u64 rB[6];
                #pragma unroll
                for (int p = 0; p < 3; ++p) {
                    rB[2*p]   = ld64ws(base + q * 8 + 256 * p);
                    rB[2*p+1] = ld64ws(base + q * 8 + 256 * p + 4);
                }
                #pragma unroll
                for (int p = 0; p < 3; ++p) {
                    u64* d = (u64*)(actb + b3 * ASTR_B + (q * 8 + 256 * p) * 2);
                    d[0] = rB[2*p]; d[1] = rB[2*p+1];
                }
                __syncthreads();
                #pragma unroll
                for (int fc = 0; fc < 6; ++fc) {
                    const int koff = ks * 192 + fc * 32 + quad * 8;
                    bf16x8 a0 = *(const bf16x8*)(actb + nl * ASTR_B + koff * 2);
                    bf16x8 a1 = *(const bf16x8*)(actb + (16 + nl) * ASTR_B + koff * 2);
                    acc0 = __builtin_amdgcn_mfma_f32_16x16x32_bf16(a0, bfr[fc], acc0, 0, 0, 0);
                    acc1 = __builtin_amdgcn_mfma_f32_16x16x32_bf16(a1, bfr[fc], acc1, 0, 0, 0);
                }
                __syncthreads();
            }

            // ---- C tiles -> red (padded; act dead) ----
            // D layout (R4-verified): col n=lane&15 (weight row), row m=quad*4+reg (batch).
            *(f32x4*)(red + (size_t)((nt * 2 + 0) * 4 + ks) * RSLAB + nl * RROW + quad * 4) = acc0;
            *(f32x4*)(red + (size_t)((nt * 2 + 1) * 4 + ks) * RSLAB + nl * RROW + quad * 4) = acc1;
            __syncthreads();

            if (role == 2) {
                const int r2 = tid >> 5, bb = tid & 31;
                const int mtr = bb >> 4, mr = bb & 15;
                const int nt0 = r2 >> 4, nr0 = r2 & 15;
                const int nt1 = (r2 + 32) >> 4, nr1 = (r2 + 32) & 15;
                float s0 = 0.f, s1 = 0.f;
                #pragma unroll
                for (int k2 = 0; k2 < 4; ++k2) {
                    s0 += red[(size_t)((nt0 * 2 + mtr) * 4 + k2) * RSLAB + nr0 * RROW + mr];
                    s1 += red[(size_t)((nt1 * 2 + mtr) * 4 + k2) * RSLAB + nr1 * RROW + mr];
                }
                const int v = s - 2;
                float* o = out + ((size_t)bb * Tt + v) * OUTF + obase;
                o[r2]      = s0 + bl0;
                o[32 + r2] = s1 + bl1;
            } else {
                // ---- fused K-reduce + gates (thread (jl,b2) owns creg) ----
                if (tid < 512) {
                    const int jl = tid >> 5, b2 = tid & 31;
                    const int mt = b2 >> 4, mr = b2 & 15;
                    float pv[4];
                    #pragma unroll
                    for (int g = 0; g < 4; ++g) {
                        float t = 0.f;
                        #pragma unroll
                        for (int k2 = 0; k2 < 4; ++k2)
                            t += red[(size_t)((g * 2 + mt) * 4 + k2) * RSLAB + jl * RROW + mr];
                        pv[g] = t;
                    }
                    const float ig = sigf(bs0 + pv[0]), fg = sigf(bs1 + pv[1]);
                    const float gv = tanhfast(bs2 + pv[2]), og = sigf(bs3 + pv[3]);
                    creg = fg * creg + ig * gv;
                    hpack[jl * 32 + b2] = f2bf(og * tanhfast(creg));
                }
                __syncthreads();
                if (tid < 256) {   // pack j-pairs -> u32 LLC store into ring
                    const int pp = tid >> 5, b2 = tid & 31;
                    const u32 val = (u32)hpack[(2 * pp) * 32 + b2]
                                  | ((u32)hpack[(2 * pp + 1) * 32 + b2] << 16);
                    u16* dst = (role == 0) ? (hA + (size_t)(s & 1) * HPS)
                                           : (hB + (size_t)((s - 1) & 1) * HPS);
                    st32ws(dst + b2 * 768 + jbase + 2 * pp, val);
                }
            }
        }

        // ---- publish progress on private line (all stores drained by barrier) ----
        __syncthreads();
        if (tid == 0) stu32(prog + wg * 32, (u32)(s + 1));
    }
}

extern "C" void kernel_launch(void* const* d_in, const int* in_sizes, int n_in,
                              void* d_out, int out_size, void* d_ws, size_t ws_size,
                              hipStream_t stream)
{
    const float* x    = (const float*)d_in[0];
    const float* Wih0 = (const float*)d_in[1];
    const float* Whh0 = (const float*)d_in[2];
    const float* bih0 = (const float*)d_in[3];
    const float* bhh0 = (const float*)d_in[4];
    const float* Wih1 = (const float*)d_in[5];
    const float* Whh1 = (const float*)d_in[6];
    const float* bih1 = (const float*)d_in[7];
    const float* bhh1 = (const float*)d_in[8];
    const float* Wlin = (const float*)d_in[9];
    const float* blin = (const float*)d_in[10];
    float* out = (float*)d_out;
    char*  ws  = (char*)d_ws;   // uses WS_BYTES = 224 KB

    hipLaunchKernelGGL(prologue, dim3(224), dim3(256), 0, stream, ws);
    hipLaunchKernelGGL(lstm_persist, dim3(NWG), dim3(NTHR), 0, stream,
                       x, Wih0, Whh0, bih0, bhh0,
                       Wih1, Whh1, bih1, bhh1,
                       Wlin, blin, out, ws);
}

// Round 7
// 6247.338 us; speedup vs baseline: 1.1177x; 1.1177x over previous
//
#include <hip/hip_runtime.h>

// Problem constants
#define Tt    1024
#define INF   256
#define Hh    768
#define OUTF  128

// Grid: 48 L0 + 48 L1 + 2 LIN WGs, 1024 thr each. No coordinator.
#define NWG_L0  48
#define NWG_L1  48
#define NWG_LIN 2
#define NWG     (NWG_L0 + NWG_L1 + NWG_LIN)   // 98
#define NTHR    1024

typedef unsigned int       u32;
typedef unsigned long long u64;
typedef unsigned short     u16;
typedef __attribute__((ext_vector_type(8))) short bf16x8;   // 8 bf16 = 4 VGPRs
typedef __attribute__((ext_vector_type(4))) float f32x4;    // MFMA C/D

// ws layout (bytes). prog[wg]: PRIVATE 128-B line, 1 writer, N pollers (reads only).
#define PROG_OFF 0                    // 98 lines x 128 B
#define HA_OFF   16384                // hA ring: [3 parity][32 b][768 j] bf16 (3 x 48 KB)
#define HB_OFF   (HA_OFF + 3*49152)   // hB ring: same
#define WS_BYTES (HB_OFF + 3*49152)   // 311,296 B
#define HPS      24576                // parity stride in u16 (32*768)

#define ASTR_B 1552        // act LDS row stride bytes (776 bf16)
#define RSLAB  272         // red slab stride (dw)
#define RROW   17          // red row stride (dw)

__device__ __forceinline__ float sigf(float v){ return 1.0f/(1.0f+__expf(-v)); }
__device__ __forceinline__ float tanhfast(float x){
    const float cx = fminf(fmaxf(x, -15.f), 15.f);
    const float e  = __expf(2.f * cx);
    return (e - 1.f) / (e + 1.f);
}
__device__ __forceinline__ u16 f2bf(float f){           // round-nearest-even
    u32 u = __float_as_uint(f);
    return (u16)((u + 0x7fffu + ((u>>16)&1u)) >> 16);
}
// LLC-coherent (L1/L2-bypassing) accesses for cross-WG data (R3/R5-proven).
__device__ __forceinline__ void st32ws(u16* p, u32 v){
    __hip_atomic_store((u32*)p, v, __ATOMIC_RELAXED, __HIP_MEMORY_SCOPE_AGENT);
}
__device__ __forceinline__ u32 ldu32(const u32* p){
    return __hip_atomic_load(p, __ATOMIC_RELAXED, __HIP_MEMORY_SCOPE_AGENT);
}
__device__ __forceinline__ void stu32(u32* p, u32 v){
    __hip_atomic_store(p, v, __ATOMIC_RELAXED, __HIP_MEMORY_SCOPE_AGENT);
}
// 16-B cache-bypassing loads, batched, single vmcnt drain. LLC is memory-side
// (always coherent with the sc-bypass atomic stores above).
__device__ __forceinline__ void ld16x3(const u16* p0, const u16* p1, const u16* p2,
                                       f32x4& r0, f32x4& r1, f32x4& r2){
    asm volatile(
        "global_load_dwordx4 %0, %3, off sc0 sc1\n\t"
        "global_load_dwordx4 %1, %4, off sc0 sc1\n\t"
        "global_load_dwordx4 %2, %5, off sc0 sc1\n\t"
        "s_waitcnt vmcnt(0)"
        : "=&v"(r0), "=&v"(r1), "=&v"(r2)
        : "v"(p0), "v"(p1), "v"(p2)
        : "memory");
}
__device__ __forceinline__ void ld16x6(const u16* p0, const u16* p1, const u16* p2,
                                       const u16* p3, const u16* p4, const u16* p5,
                                       f32x4& r0, f32x4& r1, f32x4& r2,
                                       f32x4& r3, f32x4& r4, f32x4& r5){
    asm volatile(
        "global_load_dwordx4 %0, %6, off sc0 sc1\n\t"
        "global_load_dwordx4 %1, %7, off sc0 sc1\n\t"
        "global_load_dwordx4 %2, %8, off sc0 sc1\n\t"
        "global_load_dwordx4 %3, %9, off sc0 sc1\n\t"
        "global_load_dwordx4 %4, %10, off sc0 sc1\n\t"
        "global_load_dwordx4 %5, %11, off sc0 sc1\n\t"
        "s_waitcnt vmcnt(0)"
        : "=&v"(r0), "=&v"(r1), "=&v"(r2), "=&v"(r3), "=&v"(r4), "=&v"(r5)
        : "v"(p0), "v"(p1), "v"(p2), "v"(p3), "v"(p4), "v"(p5)
        : "memory");
}

// Gang-poll cnt lines [base, base+cnt) for prog >= thr. Call from wave 0 only.
__device__ __forceinline__ void waitlines(u32* prog, int base, int cnt, u32 thr, int lane){
    bool ok = (lane >= cnt);
    int guard = 0;
    while (guard < (1 << 24)) {
        if (!ok) ok = (ldu32(prog + (base + lane) * 32) >= thr);
        if (__ballot(ok) == ~0ull) break;
        __builtin_amdgcn_s_sleep(1);
        ++guard;
    }
}

__global__ void prologue(char* ws){
    int i = blockIdx.x * 256 + threadIdx.x;
    if (i < WS_BYTES / 4)
        __hip_atomic_store(((u32*)ws) + i, 0u, __ATOMIC_RELAXED, __HIP_MEMORY_SCOPE_AGENT);
}

__device__ __forceinline__ bf16x8 load8w(const float* p){
    float4 v0 = *(const float4*)(p);
    float4 v1 = *(const float4*)(p + 4);
    bf16x8 r;
    r[0]=(short)f2bf(v0.x); r[1]=(short)f2bf(v0.y); r[2]=(short)f2bf(v0.z); r[3]=(short)f2bf(v0.w);
    r[4]=(short)f2bf(v1.x); r[5]=(short)f2bf(v1.y); r[6]=(short)f2bf(v1.z); r[7]=(short)f2bf(v1.w);
    return r;
}

__global__ __launch_bounds__(NTHR) void lstm_persist(
    const float* __restrict__ x,
    const float* __restrict__ Wih0, const float* __restrict__ Whh0,
    const float* __restrict__ bih0, const float* __restrict__ bhh0,
    const float* __restrict__ Wih1, const float* __restrict__ Whh1,
    const float* __restrict__ bih1, const float* __restrict__ bhh1,
    const float* __restrict__ Wlin, const float* __restrict__ blin,
    float* __restrict__ out, char* ws)
{
    u32* prog = (u32*)(ws + PROG_OFF);
    u16* hA   = (u16*)(ws + HA_OFF);
    u16* hB   = (u16*)(ws + HB_OFF);

    const int wg  = blockIdx.x;
    const int tid = threadIdx.x;

    __shared__ __align__(16) char smem[49664];
    char*  actb = smem;                 // [32 b][776 bf16] staging (per chunk)
    float* red  = (float*)smem;         // padded slabs; aliases act after MFMAs

    const int lane = tid & 63, w = tid >> 6;
    const int quad = lane >> 4, nl = lane & 15;
    const int nt = w >> 2, ks = w & 3;          // n-tile 0..3, K-slice 0..3
    const int b3 = tid >> 5, q = tid & 31;      // staging map: batch row, col-block

    const int role  = (wg < NWG_L0) ? 0 : ((wg < NWG_L0 + NWG_L1) ? 1 : 2);
    const int jbase = (role == 0) ? wg * 16 : ((role == 1) ? (wg - NWG_L0) * 16 : 0);
    const int obase = (role == 2) ? (wg - NWG_L0 - NWG_L1) * 64 : 0;

    // ---- register-resident bf16 weights (B-frags), loaded ONCE ----
    // B-frag layout (R4-verified): n = lane&15, k = quad*8 + j.
    bf16x8 bfr[12];
    if (role == 0) {
        const int grow = nt * Hh + jbase + nl;
        #pragma unroll
        for (int fi = 0; fi < 8; ++fi) {
            const int c = fi >> 2, fc = fi & 3;
            const int ka = c * 512 + ks * 128 + fc * 32 + quad * 8;   // K: [x(256); hA(768)]
            const float* p = (ka < 256) ? (Wih0 + (size_t)grow * 256 + ka)
                                        : (Whh0 + (size_t)grow * 768 + (ka - 256));
            bfr[fi] = load8w(p);
        }
    } else if (role == 1) {
        const int grow = nt * Hh + jbase + nl;
        #pragma unroll
        for (int fi = 0; fi < 12; ++fi) {
            const int c = fi / 6, fc = fi % 6;
            const int ka = c * 768 + ks * 192 + fc * 32 + quad * 8;   // K: [hA; hB]
            const float* p = (ka < 768) ? (Wih1 + (size_t)grow * 768 + ka)
                                        : (Whh1 + (size_t)grow * 768 + (ka - 768));
            bfr[fi] = load8w(p);
        }
    } else {
        const int row = obase + nt * 16 + nl;
        #pragma unroll
        for (int fi = 0; fi < 6; ++fi) {
            const int ka = ks * 192 + fi * 32 + quad * 8;
            bfr[fi] = load8w(Wlin + (size_t)row * 768 + ka);
        }
    }

    // gate-thread constants: tid<256 owns (jj, b2) -> j-pair {2jj, 2jj+1}; c in regs
    float ba0=0,ba1=0,ba2=0,ba3=0, bb0=0,bb1=0,bb2=0,bb3=0, creg0=0, creg1=0;
    float bl0 = 0.f, bl1 = 0.f;
    if (role < 2 && tid < 256) {
        const int jg0 = jbase + 2 * (tid >> 5), jg1 = jg0 + 1;
        const float* bi = (role == 0) ? bih0 : bih1;
        const float* bh = (role == 0) ? bhh0 : bhh1;
        ba0 = bi[jg0]        + bh[jg0];        bb0 = bi[jg1]        + bh[jg1];
        ba1 = bi[768 + jg0]  + bh[768 + jg0];  bb1 = bi[768 + jg1]  + bh[768 + jg1];
        ba2 = bi[1536 + jg0] + bh[1536 + jg0]; bb2 = bi[1536 + jg1] + bh[1536 + jg1];
        ba3 = bi[2304 + jg0] + bh[2304 + jg0]; bb3 = bi[2304 + jg1] + bh[2304 + jg1];
    }
    if (role == 2) {
        bl0 = blin[obase + (tid >> 5)];
        bl1 = blin[obase + 32 + (tid >> 5)];
    }

    for (int s = 0; s < Tt + 2; ++s) {
        const bool active = (role == 0) ? (s < Tt)
                          : (role == 1) ? (s >= 1 && s <= Tt)
                          :               (s >= 2);
        const int par_wA = s % 3;              // hA@s      (L0 write)
        const int par_rA = (s + 2) % 3;        // hA@(s-1)  (L0/L1 read; == (s-1)%3)
        const int par_wB = (s + 2) % 3;        // hB@(s-1)  (L1 write)
        const int par_rB = (s + 1) % 3;        // hB@(s-2)  (L1/LIN read)

        // ---- direct dependency polling (wave 0 gang-polls producer lines) ----
        if (active && w == 0) {
            if (role == 0) {
                if (s >= 1) waitlines(prog, 0, 48, (u32)s, lane);            // own: L0 fin s-1
                if (s >= 2) waitlines(prog, 48, 48, (u32)(s - 1), lane);     // WAR: L1 fin s-2
            } else if (role == 1) {
                waitlines(prog, 48, 48, (u32)s, lane);                       // own: L1 fin s-1
                {   // merged: L0 fin s-1 (lanes 0..47) + LIN fin s-2 (lanes 48..49)
                    const u32 thr2 = (lane < 48) ? (u32)s : (u32)(s - 1);
                    const int idx  = (lane < 48) ? lane : (96 + (lane - 48));
                    bool ok = (lane >= 50);
                    int guard = 0;
                    while (guard < (1 << 24)) {
                        if (!ok) ok = (ldu32(prog + idx * 32) >= thr2);
                        if (__ballot(ok) == ~0ull) break;
                        __builtin_amdgcn_s_sleep(1);
                        ++guard;
                    }
                }
            } else {
                waitlines(prog, 48, 48, (u32)s, lane);                       // L1 fin s-1
            }
        }
        __syncthreads();

        if (active) {
            f32x4 acc0 = {0.f,0.f,0.f,0.f}, acc1 = {0.f,0.f,0.f,0.f};

            if (role == 0) {
                const float* xs = x + ((size_t)b3 * Tt + s) * INF + q * 8;
                const float4 v0 = *(const float4*)xs;
                const float4 v1 = *(const float4*)(xs + 4);
                const u16* hp = hA + (size_t)par_rA * HPS + b3 * 768;
                f32x4 h0, h1, h2;
                ld16x3(hp + q * 8, hp + 256 + q * 8, hp + 512 + q * 8, h0, h1, h2);
                // chunk 0: cols [0,256)=x(t) bf16, [256,512)=hA[0,256)
                {
                    uint4 xv;
                    xv.x = (u32)f2bf(v0.x) | ((u32)f2bf(v0.y) << 16);
                    xv.y = (u32)f2bf(v0.z) | ((u32)f2bf(v0.w) << 16);
                    xv.z = (u32)f2bf(v1.x) | ((u32)f2bf(v1.y) << 16);
                    xv.w = (u32)f2bf(v1.z) | ((u32)f2bf(v1.w) << 16);
                    *(uint4*)(actb + b3 * ASTR_B + q * 16) = xv;
                    *(f32x4*)(actb + b3 * ASTR_B + 512 + q * 16) = h0;
                }
                __syncthreads();
                #pragma unroll
                for (int fc = 0; fc < 4; ++fc) {
                    const int koff = ks * 128 + fc * 32 + quad * 8;
                    bf16x8 a0 = *(const bf16x8*)(actb + nl * ASTR_B + koff * 2);
                    bf16x8 a1 = *(const bf16x8*)(actb + (16 + nl) * ASTR_B + koff * 2);
                    acc0 = __builtin_amdgcn_mfma_f32_16x16x32_bf16(a0, bfr[fc], acc0, 0, 0, 0);
                    acc1 = __builtin_amdgcn_mfma_f32_16x16x32_bf16(a1, bfr[fc], acc1, 0, 0, 0);
                }
                __syncthreads();
                // chunk 1: cols [0,512) = hA[256,768)
                *(f32x4*)(actb + b3 * ASTR_B + q * 16)       = h1;
                *(f32x4*)(actb + b3 * ASTR_B + 512 + q * 16) = h2;
                __syncthreads();
                #pragma unroll
                for (int fc = 0; fc < 4; ++fc) {
                    const int koff = ks * 128 + fc * 32 + quad * 8;
                    bf16x8 a0 = *(const bf16x8*)(actb + nl * ASTR_B + koff * 2);
                    bf16x8 a1 = *(const bf16x8*)(actb + (16 + nl) * ASTR_B + koff * 2);
                    acc0 = __builtin_amdgcn_mfma_f32_16x16x32_bf16(a0, bfr[4 + fc], acc0, 0, 0, 0);
                    acc1 = __builtin_amdgcn_mfma_f32_16x16x32_bf16(a1, bfr[4 + fc], acc1, 0, 0, 0);
                }
                __syncthreads();
            } else if (role == 1) {
                const u16* pA = hA + (size_t)par_rA * HPS + b3 * 768;
                const u16* pB = hB + (size_t)par_rB * HPS + b3 * 768;
                f32x4 a0, a1, a2, bq0, bq1, bq2;
                ld16x6(pA + q * 8, pA + 256 + q * 8, pA + 512 + q * 8,
                       pB + q * 8, pB + 256 + q * 8, pB + 512 + q * 8,
                       a0, a1, a2, bq0, bq1, bq2);
                // chunk 0 = hA cols [0,768)
                *(f32x4*)(actb + b3 * ASTR_B + q * 16)        = a0;
                *(f32x4*)(actb + b3 * ASTR_B + 512 + q * 16)  = a1;
                *(f32x4*)(actb + b3 * ASTR_B + 1024 + q * 16) = a2;
                __syncthreads();
                #pragma unroll
                for (int fc = 0; fc < 6; ++fc) {
                    const int koff = ks * 192 + fc * 32 + quad * 8;
                    bf16x8 f0 = *(const bf16x8*)(actb + nl * ASTR_B + koff * 2);
                    bf16x8 f1 = *(const bf16x8*)(actb + (16 + nl) * ASTR_B + koff * 2);
                    acc0 = __builtin_amdgcn_mfma_f32_16x16x32_bf16(f0, bfr[fc], acc0, 0, 0, 0);
                    acc1 = __builtin_amdgcn_mfma_f32_16x16x32_bf16(f1, bfr[fc], acc1, 0, 0, 0);
                }
                __syncthreads();
                // chunk 1 = hB cols [0,768)
                *(f32x4*)(actb + b3 * ASTR_B + q * 16)        = bq0;
                *(f32x4*)(actb + b3 * ASTR_B + 512 + q * 16)  = bq1;
                *(f32x4*)(actb + b3 * ASTR_B + 1024 + q * 16) = bq2;
                __syncthreads();
                #pragma unroll
                for (int fc = 0; fc < 6; ++fc) {
                    const int koff = ks * 192 + fc * 32 + quad * 8;
                    bf16x8 f0 = *(const bf16x8*)(actb + nl * ASTR_B + koff * 2);
                    bf16x8 f1 = *(const bf16x8*)(actb + (16 + nl) * ASTR_B + koff * 2);
                    acc0 = __builtin_amdgcn_mfma_f32_16x16x32_bf16(f0, bfr[6 + fc], acc0, 0, 0, 0);
                    acc1 = __builtin_amdgcn_mfma_f32_16x16x32_bf16(f1, bfr[6 + fc], acc1, 0, 0, 0);
                }
                __syncthreads();
            } else {
                const u16* pB = hB + (size_t)par_rB * HPS + b3 * 768;
                f32x4 bq0, bq1, bq2;
                ld16x3(pB + q * 8, pB + 256 + q * 8, pB + 512 + q * 8, bq0, bq1, bq2);
                *(f32x4*)(actb + b3 * ASTR_B + q * 16)        = bq0;
                *(f32x4*)(actb + b3 * ASTR_B + 512 + q * 16)  = bq1;
                *(f32x4*)(actb + b3 * ASTR_B + 1024 + q * 16) = bq2;
                __syncthreads();
                #pragma unroll
                for (int fc = 0; fc < 6; ++fc) {
                    const int koff = ks * 192 + fc * 32 + quad * 8;
                    bf16x8 f0 = *(const bf16x8*)(actb + nl * ASTR_B + koff * 2);
                    bf16x8 f1 = *(const bf16x8*)(actb + (16 + nl) * ASTR_B + koff * 2);
                    acc0 = __builtin_amdgcn_mfma_f32_16x16x32_bf16(f0, bfr[fc], acc0, 0, 0, 0);
                    acc1 = __builtin_amdgcn_mfma_f32_16x16x32_bf16(f1, bfr[fc], acc1, 0, 0, 0);
                }
                __syncthreads();
            }

            // ---- C tiles -> red (padded; act dead) ----
            // D layout (R4-verified): col n=lane&15 (weight row), row m=quad*4+reg (batch).
            *(f32x4*)(red + (size_t)((nt * 2 + 0) * 4 + ks) * RSLAB + nl * RROW + quad * 4) = acc0;
            *(f32x4*)(red + (size_t)((nt * 2 + 1) * 4 + ks) * RSLAB + nl * RROW + quad * 4) = acc1;
            __syncthreads();

            if (role == 2) {
                const int r2 = tid >> 5, bb = tid & 31;
                const int mtr = bb >> 4, mr = bb & 15;
                const int nt0 = r2 >> 4, nr0 = r2 & 15;
                const int nt1 = (r2 + 32) >> 4, nr1 = (r2 + 32) & 15;
                float s0 = 0.f, s1 = 0.f;
                #pragma unroll
                for (int k2 = 0; k2 < 4; ++k2) {
                    s0 += red[(size_t)((nt0 * 2 + mtr) * 4 + k2) * RSLAB + nr0 * RROW + mr];
                    s1 += red[(size_t)((nt1 * 2 + mtr) * 4 + k2) * RSLAB + nr1 * RROW + mr];
                }
                const int v = s - 2;
                float* o = out + ((size_t)bb * Tt + v) * OUTF + obase;
                o[r2]      = s0 + bl0;
                o[32 + r2] = s1 + bl1;
            } else if (tid < 256) {
                // ---- fused K-reduce + gates + direct packed h store ----
                const int jj = tid >> 5, b2 = tid & 31;
                const int mt = b2 >> 4, mr = b2 & 15;
                const int j0 = 2 * jj, j1 = 2 * jj + 1;
                float p0a=0,p1a=0,p2a=0,p3a=0, p0b=0,p1b=0,p2b=0,p3b=0;
                #pragma unroll
                for (int k2 = 0; k2 < 4; ++k2) {
                    p0a += red[(size_t)((0 * 2 + mt) * 4 + k2) * RSLAB + j0 * RROW + mr];
                    p1a += red[(size_t)((1 * 2 + mt) * 4 + k2) * RSLAB + j0 * RROW + mr];
                    p2a += red[(size_t)((2 * 2 + mt) * 4 + k2) * RSLAB + j0 * RROW + mr];
                    p3a += red[(size_t)((3 * 2 + mt) * 4 + k2) * RSLAB + j0 * RROW + mr];
                    p0b += red[(size_t)((0 * 2 + mt) * 4 + k2) * RSLAB + j1 * RROW + mr];
                    p1b += red[(size_t)((1 * 2 + mt) * 4 + k2) * RSLAB + j1 * RROW + mr];
                    p2b += red[(size_t)((2 * 2 + mt) * 4 + k2) * RSLAB + j1 * RROW + mr];
                    p3b += red[(size_t)((3 * 2 + mt) * 4 + k2) * RSLAB + j1 * RROW + mr];
                }
                const float ig0 = sigf(ba0 + p0a), fg0 = sigf(ba1 + p1a);
                const float gv0 = tanhfast(ba2 + p2a), og0 = sigf(ba3 + p3a);
                creg0 = fg0 * creg0 + ig0 * gv0;
                const float h0 = og0 * tanhfast(creg0);
                const float ig1 = sigf(bb0 + p0b), fg1 = sigf(bb1 + p1b);
                const float gv1 = tanhfast(bb2 + p2b), og1 = sigf(bb3 + p3b);
                creg1 = fg1 * creg1 + ig1 * gv1;
                const float h1 = og1 * tanhfast(creg1);
                u16* dst = (role == 0) ? (hA + (size_t)par_wA * HPS)
                                       : (hB + (size_t)par_wB * HPS);
                st32ws(dst + b2 * 768 + jbase + j0, (u32)f2bf(h0) | ((u32)f2bf(h1) << 16));
            }
        }

        // ---- publish progress (barrier drains all stores first) ----
        __syncthreads();
        if (tid == 0) stu32(prog + wg * 32, (u32)(s + 1));
    }
}

extern "C" void kernel_launch(void* const* d_in, const int* in_sizes, int n_in,
                              void* d_out, int out_size, void* d_ws, size_t ws_size,
                              hipStream_t stream)
{
    const float* x    = (const float*)d_in[0];
    const float* Wih0 = (const float*)d_in[1];
    const float* Whh0 = (const float*)d_in[2];
    const float* bih0 = (const float*)d_in[3];
    const float* bhh0 = (const float*)d_in[4];
    const float* Wih1 = (const float*)d_in[5];
    const float* Whh1 = (const float*)d_in[6];
    const float* bih1 = (const float*)d_in[7];
    const float* bhh1 = (const float*)d_in[8];
    const float* Wlin = (const float*)d_in[9];
    const float* blin = (const float*)d_in[10];
    float* out = (float*)d_out;
    char*  ws  = (char*)d_ws;   // uses WS_BYTES = 304 KB

    hipLaunchKernelGGL(prologue, dim3(304), dim3(256), 0, stream, ws);
    hipLaunchKernelGGL(lstm_persist, dim3(NWG), dim3(NTHR), 0, stream,
                       x, Wih0, Whh0, bih0, bhh0,
                       Wih1, Whh1, bih1, bhh1,
                       Wlin, blin, out, ws);
}